// Round 7
// baseline (125.573 us; speedup 1.0000x reference)
//
#include <hip/hip_runtime.h>
#include <math.h>

// RandomLowRes2D: per-image Gaussian blur (R=15, symmetric pad) + linear
// down/up resample along a per-image runtime axis.
//
// Fusion: low[j] = (1-fr)*s[la] + fr*s[la+1] collapses blur+downsample into a
// single fused filter on img: cw[k] = fmaf(fr, dwe[k], we[k+1]),
// with dwe[k] = we[k] - we[k+1] precomputed.
//
// Round 11 (fix round 10's write-side regression, keep its read-side win):
//  - ax1 LDS transpose kept (1 ds_read_b128 per tap serves 4 rows), but the
//    transposed tile is now FILLED cleanly: 4 coalesced scalar global loads
//    per column (each wave-instr reads 256 contiguous bytes of one row) +
//    ONE swizzled ds_write_b128 per column. Round 10 scattered with 8
//    ds_write_b32 at 16B lane-stride = 8-way write conflicts (why r10 was
//    flat: read win == write loss).
//  - s_lowT also swizzled (same SW involution at write+read): at res=1 the
//    upsample read is lane-stride-2 16B blocks (8-way conflict) unswizzled.
//  - ax1 upsample single pass: thread owns adjacent cols (2t, 2t+1), stores
//    4 float2 (was 8 scalar stores + 8 addr chains).
//  - ax0 path, grid order unchanged. Numerics identical (same FMA chains,
//    exact IEEE divides) -> absmax unchanged.

#define RR 15
#define TAPS 31
#define SIG_PER_FWHM 0.42466090014400953f  // 1/sqrt(8 ln 2)
#define SW(t) ((t) ^ (((t) >> 3) & 7))

__global__ __launch_bounds__(256) void lowres2d_kernel(
    const float* __restrict__ x,
    const float* __restrict__ resolution,
    const int*   __restrict__ axis,
    const float* __restrict__ gap,
    float* __restrict__ out)
{
    const int tid = threadIdx.x;
    const int n   = blockIdx.y;          // image index
    const int bx  = blockIdx.x;          // 0..127 (image-contiguous dispatch)

    const float res = resolution[n];
    const int   ax  = axis[n];
    const float gp  = gap[n];

    // ax0 images use 64 blocks of 8 rows; rest exit (block-uniform)
    if (ax == 0 && bx >= 64) return;

    const float sig = fmaxf(res * gp * SIG_PER_FWHM, 1e-6f);
    int n_low = (int)floorf(512.0f / res);
    if (n_low < 1) n_low = 1;
    if (n_low > 512) n_low = 512;
    const float nlm1f = (float)(n_low - 1);

    // adaptive radius: normalized weights < 1e-6 outside +-kr (sum >= 1)
    int kr = (int)(sig * 5.2565f) + 1;
    if (kr > RR) kr = RR;
    const int k0 = RR - kr, k1 = RR + 1 + kr;   // fused window k in [k0, k1]
    const int la_lo = kr, la_hi = 510 - kr;     // interior: no reflect needed

    // wd[k] = { we[k+1], dwe[k] }, k = 0..31; we[0]=we[32]=0 implicit
    __shared__ float2 wd[32];
    // overlaid scratch:
    //   ax1: s_imgT[512][4] (2048) + s_lowT[512][4] (2048) = 4096 floats
    //   ax0: s_lowB[9][512] = 4608 floats
    __shared__ __align__(16) float smem[4608];
    float (*s_imgT)[4]   = (float (*)[4])smem;            // swizzled blocks
    float (*s_lowT)[4]   = (float (*)[4])(smem + 2048);   // swizzled blocks
    float (*s_lowB)[512] = (float (*)[512])smem;

    if (tid < 32) {
        const int k = tid;
        float r = 0.0f;
        if (k < TAPS) {
            float d = (float)(k - RR) / sig;
            r = expf(-0.5f * d * d);
        }
        float tot = r;
        tot += __shfl_xor(tot, 1, 32);
        tot += __shfl_xor(tot, 2, 32);
        tot += __shfl_xor(tot, 4, 32);
        tot += __shfl_xor(tot, 8, 32);
        tot += __shfl_xor(tot, 16, 32);
        float rm1 = __shfl_up(r, 1, 32);
        if (k == 0) rm1 = 0.0f;
        const float inv = 1.0f / tot;            // tot >= 1 (center tap)
        wd[k] = make_float2(r * inv, (rm1 - r) * inv);
    }
    __syncthreads();

    const size_t base = (size_t)n * (512 * 512);
    const float* img = x + base;
    float* o = out + base;

    if (ax == 0) {
        // ---- ax0: cooperative low rows, float4/lane, 2 rows per pass ----
        const int i0 = bx * 8;
        const int g  = tid >> 7;                 // group 0/1 (2 waves each)
        const int lt = tid & 127;                // float4 column
        const float4* img4 = (const float4*)img;
        float4* out4 = (float4*)o;

        // needed low rows for output rows [i0, i0+8)
        float pA = fminf((float)i0 / res, nlm1f);
        int jlo = (int)floorf(pA);
        float pB = fminf((float)(i0 + 7) / res, nlm1f);
        int jhi = (int)floorf(pB) + 1;
        if (jhi > n_low - 1) jhi = n_low - 1;
        if (jhi < jlo) jhi = jlo;
        const int nrows = jhi - jlo + 1;         // <= 9 (res >= 1)

        for (int p = 0; p < nrows; p += 2) {     // block-uniform loop
            int rowoff = p + g;                  // group-uniform
            int j = jlo + ((rowoff < nrows) ? rowoff : (nrows - 1));
            float pos = fminf((float)j * res, 511.0f);
            float lof = floorf(pos);
            float fr  = pos - lof;
            int   la  = __builtin_amdgcn_readfirstlane((int)lof);
            float4 acc = make_float4(0.0f, 0.0f, 0.0f, 0.0f);
            if (la >= la_lo && la <= la_hi) {    // wave-uniform branch
                #pragma unroll 4
                for (int k = k0; k <= k1; ++k) {
                    int t = la - RR + k;         // scalar
                    float2 w = wd[k];
                    float cw = fmaf(fr, w.y, w.x);
                    float4 v = img4[(size_t)(t * 128 + lt)];
                    acc.x = fmaf(cw, v.x, acc.x);
                    acc.y = fmaf(cw, v.y, acc.y);
                    acc.z = fmaf(cw, v.z, acc.z);
                    acc.w = fmaf(cw, v.w, acc.w);
                }
            } else {
                for (int k = k0; k <= k1; ++k) {
                    int t = la - RR + k;
                    t = (t < 0)   ? (-1 - t)   : t;  // symmetric reflect
                    t = (t > 511) ? (1023 - t) : t;
                    float2 w = wd[k];
                    float cw = fmaf(fr, w.y, w.x);
                    float4 v = img4[(size_t)(t * 128 + lt)];
                    acc.x = fmaf(cw, v.x, acc.x);
                    acc.y = fmaf(cw, v.y, acc.y);
                    acc.z = fmaf(cw, v.z, acc.z);
                    acc.w = fmaf(cw, v.w, acc.w);
                }
            }
            if (rowoff < nrows) {                // group-uniform guard
                ((float4*)&s_lowB[rowoff][0])[lt] = acc;
            }
        }
        __syncthreads();

        // upsample: 2 output rows per pass, group-uniform position math
        #pragma unroll
        for (int p = 0; p < 4; ++p) {
            int i = i0 + p * 2 + g;              // group-uniform
            float pos2 = fminf((float)i / res, nlm1f);  // exact IEEE div
            float l2f  = floorf(pos2);
            float fr2  = pos2 - l2f;
            int lo2 = (int)l2f;                  // in [jlo, jhi]
            int hi2 = (lo2 + 1 <= jhi) ? (lo2 + 1) : jhi;  // == min(lo2+1, n_low-1)
            float4 A = ((float4*)&s_lowB[lo2 - jlo][0])[lt];
            float4 B = ((float4*)&s_lowB[hi2 - jlo][0])[lt];
            float omf2 = 1.0f - fr2;
            float4 ov;
            ov.x = A.x * omf2 + B.x * fr2;
            ov.y = A.y * omf2 + B.y * fr2;
            ov.z = A.z * omf2 + B.z * fr2;
            ov.w = A.w * omf2 + B.w * fr2;
            out4[(size_t)(i * 128 + lt)] = ov;
        }
    } else {
        // -------- ax1: transposed+swizzled LDS, clean b128 both ways ------
        const int h0 = bx * 4;
        const float* imgr = img + (size_t)h0 * 512;

        // fill transposed tile: 4 coalesced scalar loads per column (each
        // wave-instr = 256 contiguous bytes of one row), 1 swizzled
        // ds_write_b128 per column (dense b128 -> conflict-free).
        #pragma unroll
        for (int p = 0; p < 2; ++p) {
            int c = p * 256 + tid;
            float v0 = imgr[0 * 512 + c];
            float v1 = imgr[1 * 512 + c];
            float v2 = imgr[2 * 512 + c];
            float v3 = imgr[3 * 512 + c];
            *(float4*)&s_imgT[SW(c)][0] = make_float4(v0, v1, v2, v3);
        }
        __syncthreads();

        // low phase: one thread per low column j, all 4 rows via one
        // ds_read_b128 per tap; one swizzled ds_write_b128 per column.
        for (int j = tid; j < n_low; j += 256) {
            float pos = fminf((float)j * res, 511.0f);
            float lof = floorf(pos);
            float fr  = pos - lof;
            int   la  = (int)lof;
            float a0 = 0.0f, a1 = 0.0f, a2 = 0.0f, a3 = 0.0f;
            if (la >= la_lo && la <= la_hi) {
                #pragma unroll 4
                for (int k = k0; k <= k1; ++k) {
                    int t = la - RR + k;
                    float2 w = wd[k];
                    float cw = fmaf(fr, w.y, w.x);
                    float4 v = *(const float4*)&s_imgT[SW(t)][0];
                    a0 = fmaf(cw, v.x, a0);
                    a1 = fmaf(cw, v.y, a1);
                    a2 = fmaf(cw, v.z, a2);
                    a3 = fmaf(cw, v.w, a3);
                }
            } else {
                for (int k = k0; k <= k1; ++k) {
                    int t = la - RR + k;
                    t = (t < 0)   ? (-1 - t)   : t;  // symmetric reflect
                    t = (t > 511) ? (1023 - t) : t;
                    float2 w = wd[k];
                    float cw = fmaf(fr, w.y, w.x);
                    float4 v = *(const float4*)&s_imgT[SW(t)][0];
                    a0 = fmaf(cw, v.x, a0);
                    a1 = fmaf(cw, v.y, a1);
                    a2 = fmaf(cw, v.z, a2);
                    a3 = fmaf(cw, v.w, a3);
                }
            }
            *(float4*)&s_lowT[SW(j)][0] = make_float4(a0, a1, a2, a3);
        }
        __syncthreads();

        // upsample: thread owns adjacent cols (2t, 2t+1); 4 swizzled b128
        // reads serve 8 elements; 4 float2 stores (coalesced).
        {
            int ia = 2 * tid, ib = 2 * tid + 1;
            float posa = fminf((float)ia / res, nlm1f);  // exact IEEE div
            float posb = fminf((float)ib / res, nlm1f);
            float lfa = floorf(posa), lfb = floorf(posb);
            float fra = posa - lfa,   frb = posb - lfb;
            int loa = (int)lfa, lob = (int)lfb;
            int hia = (loa + 1 < n_low) ? (loa + 1) : (n_low - 1);
            int hib = (lob + 1 < n_low) ? (lob + 1) : (n_low - 1);
            float oma = 1.0f - fra, omb = 1.0f - frb;
            float4 Aa = *(const float4*)&s_lowT[SW(loa)][0];
            float4 Ba = *(const float4*)&s_lowT[SW(hia)][0];
            float4 Ab = *(const float4*)&s_lowT[SW(lob)][0];
            float4 Bb = *(const float4*)&s_lowT[SW(hib)][0];
            #pragma unroll
            for (int r = 0; r < 4; ++r) {
                float va = (r == 0 ? Aa.x : r == 1 ? Aa.y : r == 2 ? Aa.z : Aa.w) * oma
                         + (r == 0 ? Ba.x : r == 1 ? Ba.y : r == 2 ? Ba.z : Ba.w) * fra;
                float vb = (r == 0 ? Ab.x : r == 1 ? Ab.y : r == 2 ? Ab.z : Ab.w) * omb
                         + (r == 0 ? Bb.x : r == 1 ? Bb.y : r == 2 ? Bb.z : Bb.w) * frb;
                ((float2*)(o + (size_t)(h0 + r) * 512))[tid] = make_float2(va, vb);
            }
        }
    }
}

extern "C" void kernel_launch(void* const* d_in, const int* in_sizes, int n_in,
                              void* d_out, int out_size, void* d_ws, size_t ws_size,
                              hipStream_t stream) {
    const float* x          = (const float*)d_in[0];
    const float* resolution = (const float*)d_in[1];
    const int*   axis       = (const int*)d_in[2];
    const float* gap        = (const float*)d_in[3];
    float* out = (float*)d_out;

    const int n_img = in_sizes[1];   // B*C = 64

    dim3 grid(128, n_img);           // bx fastest: per-image sequential streaming
    lowres2d_kernel<<<grid, 256, 0, stream>>>(x, resolution, axis, gap, out);
}

// Round 8
// 120.007 us; speedup vs baseline: 1.0464x; 1.0464x over previous
//
#include <hip/hip_runtime.h>
#include <math.h>

// RandomLowRes2D: per-image Gaussian blur (R=15, symmetric pad) + linear
// down/up resample along a per-image runtime axis.
//
// Fusion: low[j] = (1-fr)*s[la] + fr*s[la+1] collapses blur+downsample into a
// single fused filter on img: cw[k] = fmaf(fr, dwe[k], we[k+1]),
// with dwe[k] = we[k] - we[k+1] precomputed.
//
// Round 12 (structural consolidation after 3 flat ax1-LDS rounds):
//  - ax1 tile = 8 rows: per-tap weight/address math serves 8 elements
//    (was 4); fills, barriers, preambles halve (64 blocks/image).
//  - grid (64, n_img): ax0 also uses 64 blocks -> the 2048 early-exit
//    no-op blocks are gone.
//  - LDS layout: 1024 16B blocks per tile, swizzled SWB(b)=b^((b>>3)&7).
//    Column c half h -> block SWB(2c+h). Lane-stride 1/2/4 cols spread
//    perfectly over the 8 bank groups; stride 8 -> 2-way (free, m136).
//  - non-temporal stores for all output (never re-read in-kernel):
//    keeps L2 for the blur's input re-reads.
//  - occupancy: 32.8 KB LDS -> 4 blocks/CU = 16 waves, at parity with the
//    measured ~50% occupancy of the 8-block config.
//  - numerics identical (same FMA chains, exact IEEE divides).

#define RR 15
#define TAPS 31
#define SIG_PER_FWHM 0.42466090014400953f  // 1/sqrt(8 ln 2)
#define SWB(b) ((b) ^ (((b) >> 3) & 7))

typedef float f4v __attribute__((ext_vector_type(4)));
typedef float f2v __attribute__((ext_vector_type(2)));

__global__ __launch_bounds__(256) void lowres2d_kernel(
    const float* __restrict__ x,
    const float* __restrict__ resolution,
    const int*   __restrict__ axis,
    const float* __restrict__ gap,
    float* __restrict__ out)
{
    const int tid = threadIdx.x;
    const int n   = blockIdx.y;          // image index
    const int bx  = blockIdx.x;          // 0..63 (image-contiguous dispatch)

    const float res = resolution[n];
    const int   ax  = axis[n];
    const float gp  = gap[n];

    const float sig = fmaxf(res * gp * SIG_PER_FWHM, 1e-6f);
    int n_low = (int)floorf(512.0f / res);
    if (n_low < 1) n_low = 1;
    if (n_low > 512) n_low = 512;
    const float nlm1f = (float)(n_low - 1);

    // adaptive radius: normalized weights < 1e-6 outside +-kr (sum >= 1)
    int kr = (int)(sig * 5.2565f) + 1;
    if (kr > RR) kr = RR;
    const int k0 = RR - kr, k1 = RR + 1 + kr;   // fused window k in [k0, k1]
    const int la_lo = kr, la_hi = 510 - kr;     // interior: no reflect needed

    // wd[k] = { we[k+1], dwe[k] }, k = 0..31; we[0]=we[32]=0 implicit
    __shared__ float2 wd[32];
    // overlaid scratch (8192 floats = 32 KB):
    //   ax1: s_imgT = blocks [0,1024), s_lowT = blocks [1024,2048)
    //        (16B blocks; column c half h -> block SWB(2c+h))
    //   ax0: s_lowB[9][512] = 4608 floats at smem base
    __shared__ __align__(16) float smem[8192];
    float (*s_imgT)[4]   = (float (*)[4])smem;
    float (*s_lowT)[4]   = (float (*)[4])(smem + 4096);
    float (*s_lowB)[512] = (float (*)[512])smem;

    if (tid < 32) {
        const int k = tid;
        float r = 0.0f;
        if (k < TAPS) {
            float d = (float)(k - RR) / sig;
            r = expf(-0.5f * d * d);
        }
        float tot = r;
        tot += __shfl_xor(tot, 1, 32);
        tot += __shfl_xor(tot, 2, 32);
        tot += __shfl_xor(tot, 4, 32);
        tot += __shfl_xor(tot, 8, 32);
        tot += __shfl_xor(tot, 16, 32);
        float rm1 = __shfl_up(r, 1, 32);
        if (k == 0) rm1 = 0.0f;
        const float inv = 1.0f / tot;            // tot >= 1 (center tap)
        wd[k] = make_float2(r * inv, (rm1 - r) * inv);
    }
    __syncthreads();

    const size_t base = (size_t)n * (512 * 512);
    const float* img = x + base;
    float* o = out + base;

    if (ax == 0) {
        // ---- ax0: cooperative low rows, float4/lane, 2 rows per pass ----
        const int i0 = bx * 8;
        const int g  = tid >> 7;                 // group 0/1 (2 waves each)
        const int lt = tid & 127;                // float4 column
        const float4* img4 = (const float4*)img;

        // needed low rows for output rows [i0, i0+8)
        float pA = fminf((float)i0 / res, nlm1f);
        int jlo = (int)floorf(pA);
        float pB = fminf((float)(i0 + 7) / res, nlm1f);
        int jhi = (int)floorf(pB) + 1;
        if (jhi > n_low - 1) jhi = n_low - 1;
        if (jhi < jlo) jhi = jlo;
        const int nrows = jhi - jlo + 1;         // <= 9 (res >= 1)

        for (int p = 0; p < nrows; p += 2) {     // block-uniform loop
            int rowoff = p + g;                  // group-uniform
            int j = jlo + ((rowoff < nrows) ? rowoff : (nrows - 1));
            float pos = fminf((float)j * res, 511.0f);
            float lof = floorf(pos);
            float fr  = pos - lof;
            int   la  = __builtin_amdgcn_readfirstlane((int)lof);
            float4 acc = make_float4(0.0f, 0.0f, 0.0f, 0.0f);
            if (la >= la_lo && la <= la_hi) {    // wave-uniform branch
                #pragma unroll 4
                for (int k = k0; k <= k1; ++k) {
                    int t = la - RR + k;         // scalar
                    float2 w = wd[k];
                    float cw = fmaf(fr, w.y, w.x);
                    float4 v = img4[(size_t)(t * 128 + lt)];
                    acc.x = fmaf(cw, v.x, acc.x);
                    acc.y = fmaf(cw, v.y, acc.y);
                    acc.z = fmaf(cw, v.z, acc.z);
                    acc.w = fmaf(cw, v.w, acc.w);
                }
            } else {
                for (int k = k0; k <= k1; ++k) {
                    int t = la - RR + k;
                    t = (t < 0)   ? (-1 - t)   : t;  // symmetric reflect
                    t = (t > 511) ? (1023 - t) : t;
                    float2 w = wd[k];
                    float cw = fmaf(fr, w.y, w.x);
                    float4 v = img4[(size_t)(t * 128 + lt)];
                    acc.x = fmaf(cw, v.x, acc.x);
                    acc.y = fmaf(cw, v.y, acc.y);
                    acc.z = fmaf(cw, v.z, acc.z);
                    acc.w = fmaf(cw, v.w, acc.w);
                }
            }
            if (rowoff < nrows) {                // group-uniform guard
                ((float4*)&s_lowB[rowoff][0])[lt] = acc;
            }
        }
        __syncthreads();

        // upsample: 2 output rows per pass, group-uniform position math
        #pragma unroll
        for (int p = 0; p < 4; ++p) {
            int i = i0 + p * 2 + g;              // group-uniform
            float pos2 = fminf((float)i / res, nlm1f);  // exact IEEE div
            float l2f  = floorf(pos2);
            float fr2  = pos2 - l2f;
            int lo2 = (int)l2f;                  // in [jlo, jhi]
            int hi2 = (lo2 + 1 <= jhi) ? (lo2 + 1) : jhi;  // == min(lo2+1, n_low-1)
            float4 A = ((float4*)&s_lowB[lo2 - jlo][0])[lt];
            float4 B = ((float4*)&s_lowB[hi2 - jlo][0])[lt];
            float omf2 = 1.0f - fr2;
            f4v ov = { A.x * omf2 + B.x * fr2,
                       A.y * omf2 + B.y * fr2,
                       A.z * omf2 + B.z * fr2,
                       A.w * omf2 + B.w * fr2 };
            __builtin_nontemporal_store(ov, (f4v*)o + (size_t)(i * 128 + lt));
        }
    } else {
        // -------- ax1: 8-row transposed+swizzled LDS tile ----------------
        const int h0 = bx * 8;
        const float* imgr = img + (size_t)h0 * 512;

        // fill: 2 columns per thread, 8 coalesced scalar loads per column
        // (each wave-instr = 256 contiguous bytes of one row), 2 swizzled
        // ds_write_b128 per column.
        #pragma unroll
        for (int p = 0; p < 2; ++p) {
            int c = p * 256 + tid;
            float v0 = imgr[0 * 512 + c];
            float v1 = imgr[1 * 512 + c];
            float v2 = imgr[2 * 512 + c];
            float v3 = imgr[3 * 512 + c];
            float v4 = imgr[4 * 512 + c];
            float v5 = imgr[5 * 512 + c];
            float v6 = imgr[6 * 512 + c];
            float v7 = imgr[7 * 512 + c];
            *(float4*)&s_imgT[SWB(2 * c + 0)][0] = make_float4(v0, v1, v2, v3);
            *(float4*)&s_imgT[SWB(2 * c + 1)][0] = make_float4(v4, v5, v6, v7);
        }
        __syncthreads();

        // low phase: one thread per low column j; per tap 2 ds_read_b128
        // serve ALL 8 rows; weight+address math amortized 8x.
        for (int j = tid; j < n_low; j += 256) {
            float pos = fminf((float)j * res, 511.0f);
            float lof = floorf(pos);
            float fr  = pos - lof;
            int   la  = (int)lof;
            float a0 = 0.f, a1 = 0.f, a2 = 0.f, a3 = 0.f;
            float a4 = 0.f, a5 = 0.f, a6 = 0.f, a7 = 0.f;
            if (la >= la_lo && la <= la_hi) {
                #pragma unroll 4
                for (int k = k0; k <= k1; ++k) {
                    int t = la - RR + k;
                    float2 w = wd[k];
                    float cw = fmaf(fr, w.y, w.x);
                    float4 u = *(const float4*)&s_imgT[SWB(2 * t + 0)][0];
                    float4 v = *(const float4*)&s_imgT[SWB(2 * t + 1)][0];
                    a0 = fmaf(cw, u.x, a0);
                    a1 = fmaf(cw, u.y, a1);
                    a2 = fmaf(cw, u.z, a2);
                    a3 = fmaf(cw, u.w, a3);
                    a4 = fmaf(cw, v.x, a4);
                    a5 = fmaf(cw, v.y, a5);
                    a6 = fmaf(cw, v.z, a6);
                    a7 = fmaf(cw, v.w, a7);
                }
            } else {
                for (int k = k0; k <= k1; ++k) {
                    int t = la - RR + k;
                    t = (t < 0)   ? (-1 - t)   : t;  // symmetric reflect
                    t = (t > 511) ? (1023 - t) : t;
                    float2 w = wd[k];
                    float cw = fmaf(fr, w.y, w.x);
                    float4 u = *(const float4*)&s_imgT[SWB(2 * t + 0)][0];
                    float4 v = *(const float4*)&s_imgT[SWB(2 * t + 1)][0];
                    a0 = fmaf(cw, u.x, a0);
                    a1 = fmaf(cw, u.y, a1);
                    a2 = fmaf(cw, u.z, a2);
                    a3 = fmaf(cw, u.w, a3);
                    a4 = fmaf(cw, v.x, a4);
                    a5 = fmaf(cw, v.y, a5);
                    a6 = fmaf(cw, v.z, a6);
                    a7 = fmaf(cw, v.w, a7);
                }
            }
            *(float4*)&s_lowT[SWB(2 * j + 0)][0] = make_float4(a0, a1, a2, a3);
            *(float4*)&s_lowT[SWB(2 * j + 1)][0] = make_float4(a4, a5, a6, a7);
        }
        __syncthreads();

        // upsample: thread owns adjacent cols (2t, 2t+1); position math per
        // column serves 8 rows; 8 swizzled b128 reads; 8 coalesced float2
        // non-temporal stores.
        {
            int ia = 2 * tid, ib = 2 * tid + 1;
            float posa = fminf((float)ia / res, nlm1f);  // exact IEEE div
            float posb = fminf((float)ib / res, nlm1f);
            float lfa = floorf(posa), lfb = floorf(posb);
            float fra = posa - lfa,   frb = posb - lfb;
            int loa = (int)lfa, lob = (int)lfb;
            int hia = (loa + 1 < n_low) ? (loa + 1) : (n_low - 1);
            int hib = (lob + 1 < n_low) ? (lob + 1) : (n_low - 1);
            float oma = 1.0f - fra, omb = 1.0f - frb;
            float4 Aa0 = *(const float4*)&s_lowT[SWB(2 * loa + 0)][0];
            float4 Aa1 = *(const float4*)&s_lowT[SWB(2 * loa + 1)][0];
            float4 Ba0 = *(const float4*)&s_lowT[SWB(2 * hia + 0)][0];
            float4 Ba1 = *(const float4*)&s_lowT[SWB(2 * hia + 1)][0];
            float4 Ab0 = *(const float4*)&s_lowT[SWB(2 * lob + 0)][0];
            float4 Ab1 = *(const float4*)&s_lowT[SWB(2 * lob + 1)][0];
            float4 Bb0 = *(const float4*)&s_lowT[SWB(2 * hib + 0)][0];
            float4 Bb1 = *(const float4*)&s_lowT[SWB(2 * hib + 1)][0];
            float Aar[8] = {Aa0.x, Aa0.y, Aa0.z, Aa0.w, Aa1.x, Aa1.y, Aa1.z, Aa1.w};
            float Bar[8] = {Ba0.x, Ba0.y, Ba0.z, Ba0.w, Ba1.x, Ba1.y, Ba1.z, Ba1.w};
            float Abr[8] = {Ab0.x, Ab0.y, Ab0.z, Ab0.w, Ab1.x, Ab1.y, Ab1.z, Ab1.w};
            float Bbr[8] = {Bb0.x, Bb0.y, Bb0.z, Bb0.w, Bb1.x, Bb1.y, Bb1.z, Bb1.w};
            #pragma unroll
            for (int r = 0; r < 8; ++r) {
                float va = Aar[r] * oma + Bar[r] * fra;
                float vb = Abr[r] * omb + Bbr[r] * frb;
                f2v ov = { va, vb };
                __builtin_nontemporal_store(
                    ov, (f2v*)(o + (size_t)(h0 + r) * 512) + tid);
            }
        }
    }
}

extern "C" void kernel_launch(void* const* d_in, const int* in_sizes, int n_in,
                              void* d_out, int out_size, void* d_ws, size_t ws_size,
                              hipStream_t stream) {
    const float* x          = (const float*)d_in[0];
    const float* resolution = (const float*)d_in[1];
    const int*   axis       = (const int*)d_in[2];
    const float* gap        = (const float*)d_in[3];
    float* out = (float*)d_out;

    const int n_img = in_sizes[1];   // B*C = 64

    dim3 grid(64, n_img);            // bx fastest: per-image sequential streaming
    lowres2d_kernel<<<grid, 256, 0, stream>>>(x, resolution, axis, gap, out);
}